// Round 6
// baseline (523.338 us; speedup 1.0000x reference)
//
#include <hip/hip_runtime.h>

typedef _Float16 f16;
typedef __attribute__((ext_vector_type(2))) _Float16 f16x2;   // SSA half2 (MFMA-compatible elt type)
typedef __attribute__((ext_vector_type(4))) _Float16 f16x4;
typedef __attribute__((ext_vector_type(8))) _Float16 f16x8;
typedef __attribute__((ext_vector_type(2))) __fp16   pk16x2;  // cvt_pkrtz return type
typedef __attribute__((ext_vector_type(4))) float    f32x4;

#define NP 13          // Wn0..6 -> p=0..6, Ws0..5 -> p=7..12; result = outputs[7]
#define THREADS 1024   // 16 waves/block, 1 block/CU (LDS ~107 KB) -> 4 waves/SIMD
#define NBLOCKS 256
#define TILES 2        // 4096 waves * 2 tiles * 32 rows = 262144

// Verified (R2-R5) conventions for mfma_f32_16x16x32_f16, D[m][n]=sum_k A[m][k]B[n][k]:
//   A/B frag: lane(q=lane>>4, l15=lane&15) holds [m|n = l15][k = q*8+j], j=0..7
//   C/D:      col(n)=l15, row(m)=q*4+reg
// A = W (m = out feature), B = h (batch row). C feeds next layer's B-frag with no
// cross-lane movement via the k-slot permutation baked into the LDS weight layout:
//   chunk ch = kb*4+q holds features kb*32 + jh*16 + q*4 + jl, XOR-swizzled by f&7.
// R6 addressing: f&7 = l15&7 -> swizzled chunk index is ft-independent -> 2 per-lane
// base pointers (kb=0/1); all weight reads = base + compile-time immediate.
//
// R11 lesson (kills the R9 "VGPR cap" theory): R8-R10's union{f16x8;f16x2[4]} h-state
// defeated SROA -> stack alloca -> 1.3 GB scratch traffic; VGPR=64 was the measured
// demand (state in memory), not a cap — both occupancy attrs were no-ops on it.
// Fix: pure-SSA packing — bit_cast(cvt_pkrtz) + shufflevector assembly; each f16x8
// fragment is built in ONE assignment. Plain vector arrays, constant indices only.

__device__ __forceinline__ f16x2 pk2(float a, float b) {
    return __builtin_bit_cast(f16x2, __builtin_amdgcn_cvt_pkrtz(a, b));
}
__device__ __forceinline__ f16x2 relu2(float a, float b) {
    const f16x2 z = { (_Float16)0.0f, (_Float16)0.0f };
    return __builtin_elementwise_max(pk2(a, b), z);
}
__device__ __forceinline__ f16x8 asm8(f16x2 a, f16x2 b, f16x2 c, f16x2 d) {
    f16x4 lo = __builtin_shufflevector(a, b, 0, 1, 2, 3);
    f16x4 hi = __builtin_shufflevector(c, d, 0, 1, 2, 3);
    return __builtin_shufflevector(lo, hi, 0, 1, 2, 3, 4, 5, 6, 7);
}
__device__ __forceinline__ f32x4 mm16(f16x8 a, f16x8 b, f32x4 c) {
    return __builtin_amdgcn_mfma_f32_16x16x32_f16(a, b, c, 0, 0, 0);
}

__attribute__((amdgpu_waves_per_eu(4, 4)))
__global__ __launch_bounds__(THREADS)
void nn_fused(const float* __restrict__ x,
              const float* __restrict__ Wn, const float* __restrict__ bn,
              const float* __restrict__ Ws, const float* __restrict__ bs,
              float* __restrict__ out)
{
    __shared__ __attribute__((aligned(16))) f16   w_lds[NP * 4096]; // [p][f=64][slot=64]
    __shared__ __attribute__((aligned(16))) float b_lds[NP * 64];   // plain f-major

    const int tid = threadIdx.x;

    // ---- stage weights (RTN casts preserve weight accuracy) ----
    for (int c = tid; c < NP * 512; c += THREADS) {
        const int p = c >> 9, f = (c >> 3) & 63, ch = c & 7;
        const int kb = ch >> 2, qq = ch & 3;
        const float* src = (p < 7 ? Wn + p * 4096 : Ws + (p - 7) * 4096) + f * 64;
        f32x4 a, b;
        __builtin_memcpy(&a, src + kb * 32 + qq * 4, 16);       // jh=0
        __builtin_memcpy(&b, src + kb * 32 + 16 + qq * 4, 16);  // jh=1
        f16x8 v;
        v[0]=(f16)a.x; v[1]=(f16)a.y; v[2]=(f16)a.z; v[3]=(f16)a.w;
        v[4]=(f16)b.x; v[5]=(f16)b.y; v[6]=(f16)b.z; v[7]=(f16)b.w;
        __builtin_memcpy(&w_lds[p * 4096 + f * 64 + ((ch ^ (f & 7)) << 3)], &v, 16);
    }
    // biases f-major: one ds_read_b128 broadcast per (p,ft); conflict-free (R8: 0 conflicts).
    for (int i = tid; i < NP * 64; i += THREADS) {
        const int p = i >> 6, f = i & 63;
        b_lds[i] = (p < 7) ? bn[p * 64 + f] : bs[(p - 7) * 64 + f];
    }
    __syncthreads();   // only barrier in the kernel

    const int lane = tid & 63;
    const int wid  = tid >> 6;
    const int l15  = lane & 15;
    const int q    = lane >> 4;
    const int q4   = q * 4;
    const int gw   = blockIdx.x * (THREADS / 64) + wid;   // 0..4095

    const int f7 = l15 & 7;
    const f16* wbn0 = &w_lds[l15 * 64 + ((q    ) ^ f7) * 8];  // kb=0 chunk base
    const f16* wbn1 = &w_lds[l15 * 64 + ((4 + q) ^ f7) * 8];  // kb=1 chunk base
    const f16* wbs0 = wbn0 + 7 * 4096;                        // skip-matrix bases (p>=7)
    const f16* wbs1 = wbn1 + 7 * 4096;

// full layer: OUT = relu(IN1 Wn[PN]^T + bn[PN]) + relu(IN2 Ws[PS7]^T + bs[7+PS7]), f16.
// Per output-half kk (ftA=2kk, ftB=2kk+1): the f16x8 B-frag for the next layer is
// assembled in one SSA assignment from four half2 values (no partial writes).
#define LAYER(PN, PS7, IN1, IN2, OUT)                                                         \
    {                                                                                         \
        _Pragma("unroll")                                                                     \
        for (int kk = 0; kk < 2; ++kk) {                                                      \
            f16x8 wnA0, wnA1, wsA0, wsA1, wnB0, wnB1, wsB0, wsB1;                             \
            __builtin_memcpy(&wnA0, wbn0 + (PN) * 4096 + (kk * 2    ) * 1024, 16);            \
            __builtin_memcpy(&wnA1, wbn1 + (PN) * 4096 + (kk * 2    ) * 1024, 16);            \
            __builtin_memcpy(&wsA0, wbs0 + (PS7) * 4096 + (kk * 2    ) * 1024, 16);           \
            __builtin_memcpy(&wsA1, wbs1 + (PS7) * 4096 + (kk * 2    ) * 1024, 16);           \
            __builtin_memcpy(&wnB0, wbn0 + (PN) * 4096 + (kk * 2 + 1) * 1024, 16);            \
            __builtin_memcpy(&wnB1, wbn1 + (PN) * 4096 + (kk * 2 + 1) * 1024, 16);            \
            __builtin_memcpy(&wsB0, wbs0 + (PS7) * 4096 + (kk * 2 + 1) * 1024, 16);           \
            __builtin_memcpy(&wsB1, wbs1 + (PS7) * 4096 + (kk * 2 + 1) * 1024, 16);           \
            f32x4 bnA, bsA, bnB, bsB;                                                         \
            __builtin_memcpy(&bnA, &b_lds[(PN) * 64 + (kk * 2    ) * 16 + q4], 16);           \
            __builtin_memcpy(&bsA, &b_lds[(7 + (PS7)) * 64 + (kk * 2    ) * 16 + q4], 16);    \
            __builtin_memcpy(&bnB, &b_lds[(PN) * 64 + (kk * 2 + 1) * 16 + q4], 16);           \
            __builtin_memcpy(&bsB, &b_lds[(7 + (PS7)) * 64 + (kk * 2 + 1) * 16 + q4], 16);    \
            _Pragma("unroll")                                                                 \
            for (int nb = 0; nb < 2; ++nb) {                                                  \
                f32x4 anA = bnA, asA = bsA, anB = bnB, asB = bsB;                             \
                anA = mm16(wnA0, IN1[nb][0], anA); anA = mm16(wnA1, IN1[nb][1], anA);         \
                asA = mm16(wsA0, IN2[nb][0], asA); asA = mm16(wsA1, IN2[nb][1], asA);         \
                anB = mm16(wnB0, IN1[nb][0], anB); anB = mm16(wnB1, IN1[nb][1], anB);         \
                asB = mm16(wsB0, IN2[nb][0], asB); asB = mm16(wsB1, IN2[nb][1], asB);         \
                f16x2 rA0 = relu2(anA[0], anA[1]) + relu2(asA[0], asA[1]);                    \
                f16x2 rA1 = relu2(anA[2], anA[3]) + relu2(asA[2], asA[3]);                    \
                f16x2 rB0 = relu2(anB[0], anB[1]) + relu2(asB[0], asB[1]);                    \
                f16x2 rB1 = relu2(anB[2], anB[3]) + relu2(asB[2], asB[3]);                    \
                OUT[nb][kk] = asm8(rA0, rA1, rB0, rB1);                                       \
            }                                                                                 \
        }                                                                                     \
    }

#pragma unroll 1
    for (int t = 0; t < TILES; ++t) {
        const long row0 = ((long)gw + (long)t * (NBLOCKS * THREADS / 64)) * 32;

        f16x8 BA[2][2], BB[2][2], BC[2][2];   // 3 rotating h buffers (plain SSA arrays)

        // ---- x -> B-frags in BB (h0) ----
#pragma unroll
        for (int nb = 0; nb < 2; ++nb) {
            const float* xr = x + (row0 + nb * 16 + l15) * 64;
#pragma unroll
            for (int kb = 0; kb < 2; ++kb) {
                f32x4 a, b;
                __builtin_memcpy(&a, xr + kb * 32 + q4, 16);
                __builtin_memcpy(&b, xr + kb * 32 + 16 + q4, 16);
                BB[nb][kb] = asm8(pk2(a.x, a.y), pk2(a.z, a.w), pk2(b.x, b.y), pk2(b.z, b.w));
            }
        }

        // ---- layer 1: BA = h1 = relu(x Wn0^T + bn0) ----
#pragma unroll
        for (int kk = 0; kk < 2; ++kk) {
            f16x8 wA0, wA1, wB0, wB1;
            __builtin_memcpy(&wA0, wbn0 + (kk * 2    ) * 1024, 16);   // p=0
            __builtin_memcpy(&wA1, wbn1 + (kk * 2    ) * 1024, 16);
            __builtin_memcpy(&wB0, wbn0 + (kk * 2 + 1) * 1024, 16);
            __builtin_memcpy(&wB1, wbn1 + (kk * 2 + 1) * 1024, 16);
            f32x4 bA, bB;
            __builtin_memcpy(&bA, &b_lds[(kk * 2    ) * 16 + q4], 16);
            __builtin_memcpy(&bB, &b_lds[(kk * 2 + 1) * 16 + q4], 16);
#pragma unroll
            for (int nb = 0; nb < 2; ++nb) {
                f32x4 anA = bA, anB = bB;
                anA = mm16(wA0, BB[nb][0], anA); anA = mm16(wA1, BB[nb][1], anA);
                anB = mm16(wB0, BB[nb][0], anB); anB = mm16(wB1, BB[nb][1], anB);
                BA[nb][kk] = asm8(relu2(anA[0], anA[1]), relu2(anA[2], anA[3]),
                                  relu2(anB[0], anB[1]), relu2(anB[2], anB[3]));
            }
        }

        // ---- layers 2..6, period-3 buffer rotation (in1=h_{l-1}, in2=h_{l-2}, out over dead) ----
        LAYER(1, 0, BA, BB, BC);   // l=2: h2
        LAYER(2, 1, BC, BA, BB);   // l=3: h3
        LAYER(3, 2, BB, BC, BA);   // l=4: h4
        LAYER(4, 3, BA, BB, BC);   // l=5: h5
        LAYER(5, 4, BC, BA, BB);   // l=6: h6

        // ---- layer 7: out = relu(h6 Wn6^T + bn6) + relu(h5 Ws5^T + bs5), fp32 store ----
#pragma unroll
        for (int ft = 0; ft < 4; ++ft) {
            f16x8 wn0, wn1, ws0, ws1;
            __builtin_memcpy(&wn0, wbn0 + 6 * 4096 + ft * 1024, 16);
            __builtin_memcpy(&wn1, wbn1 + 6 * 4096 + ft * 1024, 16);
            __builtin_memcpy(&ws0, wbs0 + 5 * 4096 + ft * 1024, 16);
            __builtin_memcpy(&ws1, wbs1 + 5 * 4096 + ft * 1024, 16);
            f32x4 bnv, bsv;
            __builtin_memcpy(&bnv, &b_lds[6 * 64 + ft * 16 + q4], 16);
            __builtin_memcpy(&bsv, &b_lds[12 * 64 + ft * 16 + q4], 16);
#pragma unroll
            for (int nb = 0; nb < 2; ++nb) {
                f32x4 an = bnv, as = bsv;
                an = mm16(wn0, BB[nb][0], an); an = mm16(wn1, BB[nb][1], an);
                as = mm16(ws0, BC[nb][0], as); as = mm16(ws1, BC[nb][1], as);
                f32x4 v;
#pragma unroll
                for (int r = 0; r < 4; ++r) v[r] = fmaxf(an[r], 0.f) + fmaxf(as[r], 0.f);
                float* orow = out + (row0 + nb * 16 + l15) * 64;
                __builtin_memcpy(orow + ft * 16 + q4, &v, 16);
            }
        }
    }
#undef LAYER
}

extern "C" void kernel_launch(void* const* d_in, const int* in_sizes, int n_in,
                              void* d_out, int out_size, void* d_ws, size_t ws_size,
                              hipStream_t stream) {
    (void)in_sizes; (void)n_in; (void)d_ws; (void)ws_size; (void)out_size;
    const float* x  = (const float*)d_in[0];
    const float* Wn = (const float*)d_in[1];
    const float* bn = (const float*)d_in[2];
    const float* Ws = (const float*)d_in[3];
    const float* bs = (const float*)d_in[4];
    nn_fused<<<dim3(NBLOCKS), dim3(THREADS), 0, stream>>>(x, Wn, bn, Ws, bs, (float*)d_out);
}

// Round 7
// 377.871 us; speedup vs baseline: 1.3850x; 1.3850x over previous
//
#include <hip/hip_runtime.h>

typedef _Float16 f16;
typedef __attribute__((ext_vector_type(2))) _Float16 f16x2;   // SSA half2 (MFMA-compatible elt type)
typedef __attribute__((ext_vector_type(4))) _Float16 f16x4;
typedef __attribute__((ext_vector_type(8))) _Float16 f16x8;
typedef __attribute__((ext_vector_type(4))) float    f32x4;

#define NP 13          // Wn0..6 -> p=0..6, Ws0..5 -> p=7..12; result = outputs[7]
#define THREADS 512    // 8 waves/block, 1 block/CU (LDS ~107 KB) -> 2 waves/SIMD
#define NBLOCKS 256
#define TILES 4        // 2048 waves * 4 tiles * 32 rows = 262144

// Verified (R2-R5) conventions for mfma_f32_16x16x32_f16, D[m][n]=sum_k A[m][k]B[n][k]:
//   A/B frag: lane(q=lane>>4, l15=lane&15) holds [m|n = l15][k = q*8+j], j=0..7
//   C/D:      col(n)=l15, row(m)=q*4+reg
// A = W (m = out feature), B = h (batch row). C feeds next layer's B-frag with no
// cross-lane movement via the k-slot permutation baked into the LDS weight layout:
//   chunk ch = kb*4+q holds features kb*32 + jh*16 + q*4 + jl, XOR-swizzled by f&7.
// R6 addressing: f&7 = l15&7 -> swizzled chunk index is ft-independent -> 2 per-lane
// base pointers (kb=0/1); all weight reads = base + compile-time immediate.
//
// R12 decision: 1024-thread workgroups on this toolchain ALWAYS build at 64 VGPR
// (R8-R11: 3 code shapes x 2 occupancy attrs, identical 64/112 fingerprint, ~1.3 GB
// scratch). Closed. 512-thread builds allocate sanely (R0: 124 VGPR, no spill).
// This round = R0's proven 512-thread shape + the R6/R11 VALU trims:
//   SSA packed epilogue (cvt_pkrtz+shufflevector), immediate-offset weight reads,
//   b128 bias broadcast, period-3 rotation (no inter-layer copies).

__device__ __forceinline__ f16x2 pk2(float a, float b) {
    return __builtin_bit_cast(f16x2, __builtin_amdgcn_cvt_pkrtz(a, b));
}
__device__ __forceinline__ f16x2 relu2(float a, float b) {
    const f16x2 z = { (_Float16)0.0f, (_Float16)0.0f };
    return __builtin_elementwise_max(pk2(a, b), z);
}
__device__ __forceinline__ f16x8 asm8(f16x2 a, f16x2 b, f16x2 c, f16x2 d) {
    f16x4 lo = __builtin_shufflevector(a, b, 0, 1, 2, 3);
    f16x4 hi = __builtin_shufflevector(c, d, 0, 1, 2, 3);
    return __builtin_shufflevector(lo, hi, 0, 1, 2, 3, 4, 5, 6, 7);
}
__device__ __forceinline__ f32x4 mm16(f16x8 a, f16x8 b, f32x4 c) {
    return __builtin_amdgcn_mfma_f32_16x16x32_f16(a, b, c, 0, 0, 0);
}

__global__ __launch_bounds__(THREADS)
void nn_fused(const float* __restrict__ x,
              const float* __restrict__ Wn, const float* __restrict__ bn,
              const float* __restrict__ Ws, const float* __restrict__ bs,
              float* __restrict__ out)
{
    __shared__ __attribute__((aligned(16))) f16   w_lds[NP * 4096]; // [p][f=64][slot=64]
    __shared__ __attribute__((aligned(16))) float b_lds[NP * 64];   // plain f-major

    const int tid = threadIdx.x;

    // ---- stage weights (RTN casts preserve weight accuracy) ----
    for (int c = tid; c < NP * 512; c += THREADS) {
        const int p = c >> 9, f = (c >> 3) & 63, ch = c & 7;
        const int kb = ch >> 2, qq = ch & 3;
        const float* src = (p < 7 ? Wn + p * 4096 : Ws + (p - 7) * 4096) + f * 64;
        f32x4 a, b;
        __builtin_memcpy(&a, src + kb * 32 + qq * 4, 16);       // jh=0
        __builtin_memcpy(&b, src + kb * 32 + 16 + qq * 4, 16);  // jh=1
        f16x8 v;
        v[0]=(f16)a.x; v[1]=(f16)a.y; v[2]=(f16)a.z; v[3]=(f16)a.w;
        v[4]=(f16)b.x; v[5]=(f16)b.y; v[6]=(f16)b.z; v[7]=(f16)b.w;
        __builtin_memcpy(&w_lds[p * 4096 + f * 64 + ((ch ^ (f & 7)) << 3)], &v, 16);
    }
    // biases f-major: one ds_read_b128 broadcast per (p,ft); conflict-free (R8: 0 conflicts).
    for (int i = tid; i < NP * 64; i += THREADS) {
        const int p = i >> 6, f = i & 63;
        b_lds[i] = (p < 7) ? bn[p * 64 + f] : bs[(p - 7) * 64 + f];
    }
    __syncthreads();   // only barrier in the kernel

    const int lane = tid & 63;
    const int wid  = tid >> 6;
    const int l15  = lane & 15;
    const int q    = lane >> 4;
    const int q4   = q * 4;
    const int gw   = blockIdx.x * (THREADS / 64) + wid;   // 0..2047

    const int f7 = l15 & 7;
    const f16* wbn0 = &w_lds[l15 * 64 + ((q    ) ^ f7) * 8];  // kb=0 chunk base
    const f16* wbn1 = &w_lds[l15 * 64 + ((4 + q) ^ f7) * 8];  // kb=1 chunk base
    const f16* wbs0 = wbn0 + 7 * 4096;                        // skip-matrix bases (p>=7)
    const f16* wbs1 = wbn1 + 7 * 4096;

// full layer: OUT = relu(IN1 Wn[PN]^T + bn[PN]) + relu(IN2 Ws[PS7]^T + bs[7+PS7]), f16.
// Per output-half kk (ftA=2kk, ftB=2kk+1): next layer's f16x8 B-frag assembled in one
// SSA assignment from four half2 values (no partial writes -> stays in registers).
#define LAYER(PN, PS7, IN1, IN2, OUT)                                                         \
    {                                                                                         \
        _Pragma("unroll")                                                                     \
        for (int kk = 0; kk < 2; ++kk) {                                                      \
            f16x8 wnA0, wnA1, wsA0, wsA1, wnB0, wnB1, wsB0, wsB1;                             \
            __builtin_memcpy(&wnA0, wbn0 + (PN) * 4096 + (kk * 2    ) * 1024, 16);            \
            __builtin_memcpy(&wnA1, wbn1 + (PN) * 4096 + (kk * 2    ) * 1024, 16);            \
            __builtin_memcpy(&wsA0, wbs0 + (PS7) * 4096 + (kk * 2    ) * 1024, 16);           \
            __builtin_memcpy(&wsA1, wbs1 + (PS7) * 4096 + (kk * 2    ) * 1024, 16);           \
            __builtin_memcpy(&wnB0, wbn0 + (PN) * 4096 + (kk * 2 + 1) * 1024, 16);            \
            __builtin_memcpy(&wnB1, wbn1 + (PN) * 4096 + (kk * 2 + 1) * 1024, 16);            \
            __builtin_memcpy(&wsB0, wbs0 + (PS7) * 4096 + (kk * 2 + 1) * 1024, 16);           \
            __builtin_memcpy(&wsB1, wbs1 + (PS7) * 4096 + (kk * 2 + 1) * 1024, 16);           \
            f32x4 bnA, bsA, bnB, bsB;                                                         \
            __builtin_memcpy(&bnA, &b_lds[(PN) * 64 + (kk * 2    ) * 16 + q4], 16);           \
            __builtin_memcpy(&bsA, &b_lds[(7 + (PS7)) * 64 + (kk * 2    ) * 16 + q4], 16);    \
            __builtin_memcpy(&bnB, &b_lds[(PN) * 64 + (kk * 2 + 1) * 16 + q4], 16);           \
            __builtin_memcpy(&bsB, &b_lds[(7 + (PS7)) * 64 + (kk * 2 + 1) * 16 + q4], 16);    \
            _Pragma("unroll")                                                                 \
            for (int nb = 0; nb < 2; ++nb) {                                                  \
                f32x4 anA = bnA, asA = bsA, anB = bnB, asB = bsB;                             \
                anA = mm16(wnA0, IN1[nb][0], anA); anA = mm16(wnA1, IN1[nb][1], anA);         \
                asA = mm16(wsA0, IN2[nb][0], asA); asA = mm16(wsA1, IN2[nb][1], asA);         \
                anB = mm16(wnB0, IN1[nb][0], anB); anB = mm16(wnB1, IN1[nb][1], anB);         \
                asB = mm16(wsB0, IN2[nb][0], asB); asB = mm16(wsB1, IN2[nb][1], asB);         \
                f16x2 rA0 = relu2(anA[0], anA[1]) + relu2(asA[0], asA[1]);                    \
                f16x2 rA1 = relu2(anA[2], anA[3]) + relu2(asA[2], asA[3]);                    \
                f16x2 rB0 = relu2(anB[0], anB[1]) + relu2(asB[0], asB[1]);                    \
                f16x2 rB1 = relu2(anB[2], anB[3]) + relu2(asB[2], asB[3]);                    \
                OUT[nb][kk] = asm8(rA0, rA1, rB0, rB1);                                       \
            }                                                                                 \
        }                                                                                     \
    }

#pragma unroll 1
    for (int t = 0; t < TILES; ++t) {
        const long row0 = ((long)gw + (long)t * (NBLOCKS * THREADS / 64)) * 32;

        f16x8 BA[2][2], BB[2][2], BC[2][2];   // 3 rotating h buffers (plain SSA arrays)

        // ---- x -> B-frags in BB (h0) ----
#pragma unroll
        for (int nb = 0; nb < 2; ++nb) {
            const float* xr = x + (row0 + nb * 16 + l15) * 64;
#pragma unroll
            for (int kb = 0; kb < 2; ++kb) {
                f32x4 a, b;
                __builtin_memcpy(&a, xr + kb * 32 + q4, 16);
                __builtin_memcpy(&b, xr + kb * 32 + 16 + q4, 16);
                BB[nb][kb] = asm8(pk2(a.x, a.y), pk2(a.z, a.w), pk2(b.x, b.y), pk2(b.z, b.w));
            }
        }

        // ---- layer 1: BA = h1 = relu(x Wn0^T + bn0) ----
#pragma unroll
        for (int kk = 0; kk < 2; ++kk) {
            f16x8 wA0, wA1, wB0, wB1;
            __builtin_memcpy(&wA0, wbn0 + (kk * 2    ) * 1024, 16);   // p=0
            __builtin_memcpy(&wA1, wbn1 + (kk * 2    ) * 1024, 16);
            __builtin_memcpy(&wB0, wbn0 + (kk * 2 + 1) * 1024, 16);
            __builtin_memcpy(&wB1, wbn1 + (kk * 2 + 1) * 1024, 16);
            f32x4 bA, bB;
            __builtin_memcpy(&bA, &b_lds[(kk * 2    ) * 16 + q4], 16);
            __builtin_memcpy(&bB, &b_lds[(kk * 2 + 1) * 16 + q4], 16);
#pragma unroll
            for (int nb = 0; nb < 2; ++nb) {
                f32x4 anA = bA, anB = bB;
                anA = mm16(wA0, BB[nb][0], anA); anA = mm16(wA1, BB[nb][1], anA);
                anB = mm16(wB0, BB[nb][0], anB); anB = mm16(wB1, BB[nb][1], anB);
                BA[nb][kk] = asm8(relu2(anA[0], anA[1]), relu2(anA[2], anA[3]),
                                  relu2(anB[0], anB[1]), relu2(anB[2], anB[3]));
            }
        }

        // ---- layers 2..6, period-3 buffer rotation (in1=h_{l-1}, in2=h_{l-2}, out over dead) ----
        LAYER(1, 0, BA, BB, BC);   // l=2: h2
        LAYER(2, 1, BC, BA, BB);   // l=3: h3
        LAYER(3, 2, BB, BC, BA);   // l=4: h4
        LAYER(4, 3, BA, BB, BC);   // l=5: h5
        LAYER(5, 4, BC, BA, BB);   // l=6: h6

        // ---- layer 7: out = relu(h6 Wn6^T + bn6) + relu(h5 Ws5^T + bs5), fp32 store ----
#pragma unroll
        for (int ft = 0; ft < 4; ++ft) {
            f16x8 wn0, wn1, ws0, ws1;
            __builtin_memcpy(&wn0, wbn0 + 6 * 4096 + ft * 1024, 16);
            __builtin_memcpy(&wn1, wbn1 + 6 * 4096 + ft * 1024, 16);
            __builtin_memcpy(&ws0, wbs0 + 5 * 4096 + ft * 1024, 16);
            __builtin_memcpy(&ws1, wbs1 + 5 * 4096 + ft * 1024, 16);
            f32x4 bnv, bsv;
            __builtin_memcpy(&bnv, &b_lds[6 * 64 + ft * 16 + q4], 16);
            __builtin_memcpy(&bsv, &b_lds[12 * 64 + ft * 16 + q4], 16);
#pragma unroll
            for (int nb = 0; nb < 2; ++nb) {
                f32x4 an = bnv, as = bsv;
                an = mm16(wn0, BB[nb][0], an); an = mm16(wn1, BB[nb][1], an);
                as = mm16(ws0, BC[nb][0], as); as = mm16(ws1, BC[nb][1], as);
                f32x4 v;
#pragma unroll
                for (int r = 0; r < 4; ++r) v[r] = fmaxf(an[r], 0.f) + fmaxf(as[r], 0.f);
                float* orow = out + (row0 + nb * 16 + l15) * 64;
                __builtin_memcpy(orow + ft * 16 + q4, &v, 16);
            }
        }
    }
#undef LAYER
}

extern "C" void kernel_launch(void* const* d_in, const int* in_sizes, int n_in,
                              void* d_out, int out_size, void* d_ws, size_t ws_size,
                              hipStream_t stream) {
    (void)in_sizes; (void)n_in; (void)d_ws; (void)ws_size; (void)out_size;
    const float* x  = (const float*)d_in[0];
    const float* Wn = (const float*)d_in[1];
    const float* bn = (const float*)d_in[2];
    const float* Ws = (const float*)d_in[3];
    const float* bs = (const float*)d_in[4];
    nn_fused<<<dim3(NBLOCKS), dim3(THREADS), 0, stream>>>(x, Wn, bn, Ws, bs, (float*)d_out);
}

// Round 8
// 361.704 us; speedup vs baseline: 1.4469x; 1.0447x over previous
//
#include <hip/hip_runtime.h>

typedef _Float16 f16;
typedef __attribute__((ext_vector_type(2))) _Float16 f16x2;   // SSA half2
typedef __attribute__((ext_vector_type(8))) _Float16 f16x8;
typedef __attribute__((ext_vector_type(4))) float    f32x4;

#define NP 13          // Wn0..6 -> p=0..6, Ws0..5 -> p=7..12; result = outputs[7]
#define THREADS 512    // 8 waves/block, 1 block/CU (LDS ~107 KB) -> 2 waves/SIMD
#define NBLOCKS 256
#define TILES 4        // 2048 waves * 4 tiles * 32 rows = 262144

// Verified (R2-R5) conventions for mfma_f32_16x16x32_f16, D[m][n]=sum_k A[m][k]B[n][k]:
//   A/B frag: lane(q=lane>>4, l15=lane&15) holds [m|n = l15][k = q*8+j], j=0..7
//   C/D:      col(n)=l15, row(m)=q*4+reg
// A = W (m = out feature), B = h (batch row). C feeds next layer's B-frag with no
// cross-lane movement via the k-slot permutation baked into the LDS weight layout:
//   chunk ch = kb*4+q holds features kb*32 + jh*16 + q*4 + jl, XOR-swizzled by f&7.
// R6 addressing: f&7 = l15&7 -> swizzled chunk index is ft-independent -> 2 per-lane
// base pointers (kb=0/1); all weight reads = base + compile-time immediate.
//
// Register law (R3-R5, reconfirmed R12): 512-thread builds cap at 128 VGPR; the
// binding constraint is LIVE SET, not code shape. R12's per-kk LAYER (8 wfrags +
// 4 biases + 4 accums live = ~160 demand) spilled 0.8 GB. This round: R0's per-ft
// granularity (4 wfrags + 2 biases + 2 accums live, ~124 demand proven) + only
// register-neutral trims: immediate-offset reads, b128 bias, rotation, packed relu.
// 1024-thread shape: closed (R8-R11, always 64 VGPR -> 1.3 GB scratch).

__device__ __forceinline__ f16x2 pk2(float a, float b) {
    return __builtin_bit_cast(f16x2, __builtin_amdgcn_cvt_pkrtz(a, b));
}
__device__ __forceinline__ f16x2 relu2(float a, float b) {
    const f16x2 z = { (_Float16)0.0f, (_Float16)0.0f };
    return __builtin_elementwise_max(pk2(a, b), z);
}
__device__ __forceinline__ f32x4 mm16(f16x8 a, f16x8 b, f32x4 c) {
    return __builtin_amdgcn_mfma_f32_16x16x32_f16(a, b, c, 0, 0, 0);
}

__global__ __launch_bounds__(THREADS)
void nn_fused(const float* __restrict__ x,
              const float* __restrict__ Wn, const float* __restrict__ bn,
              const float* __restrict__ Ws, const float* __restrict__ bs,
              float* __restrict__ out)
{
    __shared__ __attribute__((aligned(16))) f16   w_lds[NP * 4096]; // [p][f=64][slot=64]
    __shared__ __attribute__((aligned(16))) float b_lds[NP * 64];   // plain f-major

    const int tid = threadIdx.x;

    // ---- stage weights (RTN casts preserve weight accuracy) ----
    for (int c = tid; c < NP * 512; c += THREADS) {
        const int p = c >> 9, f = (c >> 3) & 63, ch = c & 7;
        const int kb = ch >> 2, qq = ch & 3;
        const float* src = (p < 7 ? Wn + p * 4096 : Ws + (p - 7) * 4096) + f * 64;
        f32x4 a, b;
        __builtin_memcpy(&a, src + kb * 32 + qq * 4, 16);       // jh=0
        __builtin_memcpy(&b, src + kb * 32 + 16 + qq * 4, 16);  // jh=1
        f16x8 v;
        v[0]=(f16)a.x; v[1]=(f16)a.y; v[2]=(f16)a.z; v[3]=(f16)a.w;
        v[4]=(f16)b.x; v[5]=(f16)b.y; v[6]=(f16)b.z; v[7]=(f16)b.w;
        __builtin_memcpy(&w_lds[p * 4096 + f * 64 + ((ch ^ (f & 7)) << 3)], &v, 16);
    }
    // biases f-major: one ds_read_b128 broadcast per (p,ft); conflict-free (R8: 0 conflicts).
    for (int i = tid; i < NP * 64; i += THREADS) {
        const int p = i >> 6, f = i & 63;
        b_lds[i] = (p < 7) ? bn[p * 64 + f] : bs[(p - 7) * 64 + f];
    }
    __syncthreads();   // only barrier in the kernel

    const int lane = tid & 63;
    const int wid  = tid >> 6;
    const int l15  = lane & 15;
    const int q    = lane >> 4;
    const int q4   = q * 4;
    const int gw   = blockIdx.x * (THREADS / 64) + wid;   // 0..2047

    const int f7 = l15 & 7;
    const f16* wbn0 = &w_lds[l15 * 64 + ((q    ) ^ f7) * 8];  // kb=0 chunk base
    const f16* wbn1 = &w_lds[l15 * 64 + ((4 + q) ^ f7) * 8];  // kb=1 chunk base
    const f16* wbs0 = wbn0 + 7 * 4096;                        // skip-matrix bases (p>=7)
    const f16* wbs1 = wbn1 + 7 * 4096;

// full layer: OUT = relu(IN1 Wn[PN]^T + bn[PN]) + relu(IN2 Ws[PS7]^T + bs[7+PS7]), f16.
// Per-ft granularity (R0's proven live set): 4 wfrags + 2 biases + 2 accums live.
// Packed epilogue; results land as SSA element inserts (R0's proven write pattern).
#define LAYER(PN, PS7, IN1, IN2, OUT)                                                         \
    {                                                                                         \
        _Pragma("unroll")                                                                     \
        for (int ft = 0; ft < 4; ++ft) {                                                      \
            f16x8 wn0, wn1, ws0, ws1;                                                         \
            __builtin_memcpy(&wn0, wbn0 + (PN) * 4096 + ft * 1024, 16);                       \
            __builtin_memcpy(&wn1, wbn1 + (PN) * 4096 + ft * 1024, 16);                       \
            __builtin_memcpy(&ws0, wbs0 + (PS7) * 4096 + ft * 1024, 16);                      \
            __builtin_memcpy(&ws1, wbs1 + (PS7) * 4096 + ft * 1024, 16);                      \
            f32x4 bnv, bsv;                                                                   \
            __builtin_memcpy(&bnv, &b_lds[(PN) * 64 + ft * 16 + q4], 16);                     \
            __builtin_memcpy(&bsv, &b_lds[(7 + (PS7)) * 64 + ft * 16 + q4], 16);              \
            _Pragma("unroll")                                                                 \
            for (int nb = 0; nb < 2; ++nb) {                                                  \
                f32x4 an = bnv, as = bsv;                                                     \
                an = mm16(wn0, IN1[nb][0], an); an = mm16(wn1, IN1[nb][1], an);               \
                as = mm16(ws0, IN2[nb][0], as); as = mm16(ws1, IN2[nb][1], as);               \
                f16x2 r0 = relu2(an[0], an[1]) + relu2(as[0], as[1]);                         \
                f16x2 r1 = relu2(an[2], an[3]) + relu2(as[2], as[3]);                         \
                OUT[nb][ft >> 1][(ft & 1) * 4 + 0] = r0[0];                                   \
                OUT[nb][ft >> 1][(ft & 1) * 4 + 1] = r0[1];                                   \
                OUT[nb][ft >> 1][(ft & 1) * 4 + 2] = r1[0];                                   \
                OUT[nb][ft >> 1][(ft & 1) * 4 + 3] = r1[1];                                   \
            }                                                                                 \
        }                                                                                     \
    }

#pragma unroll 1
    for (int t = 0; t < TILES; ++t) {
        const long row0 = ((long)gw + (long)t * (NBLOCKS * THREADS / 64)) * 32;

        f16x8 BA[2][2], BB[2][2], BC[2][2];   // 3 rotating h buffers (plain SSA arrays)

        // ---- x -> B-frags in BB (h0) ----
#pragma unroll
        for (int nb = 0; nb < 2; ++nb) {
            const float* xr = x + (row0 + nb * 16 + l15) * 64;
#pragma unroll
            for (int kb = 0; kb < 2; ++kb) {
                f32x4 a, b;
                __builtin_memcpy(&a, xr + kb * 32 + q4, 16);
                __builtin_memcpy(&b, xr + kb * 32 + 16 + q4, 16);
                f16x2 p0 = pk2(a.x, a.y), p1 = pk2(a.z, a.w);
                f16x2 p2 = pk2(b.x, b.y), p3 = pk2(b.z, b.w);
                BB[nb][kb][0] = p0[0]; BB[nb][kb][1] = p0[1];
                BB[nb][kb][2] = p1[0]; BB[nb][kb][3] = p1[1];
                BB[nb][kb][4] = p2[0]; BB[nb][kb][5] = p2[1];
                BB[nb][kb][6] = p3[0]; BB[nb][kb][7] = p3[1];
            }
        }

        // ---- layer 1: BA = h1 = relu(x Wn0^T + bn0) ----
#pragma unroll
        for (int ft = 0; ft < 4; ++ft) {
            f16x8 w0, w1;
            __builtin_memcpy(&w0, wbn0 + ft * 1024, 16);   // p=0
            __builtin_memcpy(&w1, wbn1 + ft * 1024, 16);
            f32x4 bv;
            __builtin_memcpy(&bv, &b_lds[ft * 16 + q4], 16);
#pragma unroll
            for (int nb = 0; nb < 2; ++nb) {
                f32x4 an = bv;
                an = mm16(w0, BB[nb][0], an);
                an = mm16(w1, BB[nb][1], an);
                f16x2 r0 = relu2(an[0], an[1]);
                f16x2 r1 = relu2(an[2], an[3]);
                BA[nb][ft >> 1][(ft & 1) * 4 + 0] = r0[0];
                BA[nb][ft >> 1][(ft & 1) * 4 + 1] = r0[1];
                BA[nb][ft >> 1][(ft & 1) * 4 + 2] = r1[0];
                BA[nb][ft >> 1][(ft & 1) * 4 + 3] = r1[1];
            }
        }

        // ---- layers 2..6, period-3 buffer rotation (in1=h_{l-1}, in2=h_{l-2}, out over dead) ----
        LAYER(1, 0, BA, BB, BC);   // l=2: h2
        LAYER(2, 1, BC, BA, BB);   // l=3: h3
        LAYER(3, 2, BB, BC, BA);   // l=4: h4
        LAYER(4, 3, BA, BB, BC);   // l=5: h5
        LAYER(5, 4, BC, BA, BB);   // l=6: h6

        // ---- layer 7: out = relu(h6 Wn6^T + bn6) + relu(h5 Ws5^T + bs5), fp32 store ----
#pragma unroll
        for (int ft = 0; ft < 4; ++ft) {
            f16x8 wn0, wn1, ws0, ws1;
            __builtin_memcpy(&wn0, wbn0 + 6 * 4096 + ft * 1024, 16);
            __builtin_memcpy(&wn1, wbn1 + 6 * 4096 + ft * 1024, 16);
            __builtin_memcpy(&ws0, wbs0 + 5 * 4096 + ft * 1024, 16);
            __builtin_memcpy(&ws1, wbs1 + 5 * 4096 + ft * 1024, 16);
            f32x4 bnv, bsv;
            __builtin_memcpy(&bnv, &b_lds[6 * 64 + ft * 16 + q4], 16);
            __builtin_memcpy(&bsv, &b_lds[12 * 64 + ft * 16 + q4], 16);
#pragma unroll
            for (int nb = 0; nb < 2; ++nb) {
                f32x4 an = bnv, as = bsv;
                an = mm16(wn0, BB[nb][0], an); an = mm16(wn1, BB[nb][1], an);
                as = mm16(ws0, BC[nb][0], as); as = mm16(ws1, BC[nb][1], as);
                f32x4 v;
#pragma unroll
                for (int r = 0; r < 4; ++r) v[r] = fmaxf(an[r], 0.f) + fmaxf(as[r], 0.f);
                float* orow = out + (row0 + nb * 16 + l15) * 64;
                __builtin_memcpy(orow + ft * 16 + q4, &v, 16);
            }
        }
    }
#undef LAYER
}

extern "C" void kernel_launch(void* const* d_in, const int* in_sizes, int n_in,
                              void* d_out, int out_size, void* d_ws, size_t ws_size,
                              hipStream_t stream) {
    (void)in_sizes; (void)n_in; (void)d_ws; (void)ws_size; (void)out_size;
    const float* x  = (const float*)d_in[0];
    const float* Wn = (const float*)d_in[1];
    const float* bn = (const float*)d_in[2];
    const float* Ws = (const float*)d_in[3];
    const float* bs = (const float*)d_in[4];
    nn_fused<<<dim3(NBLOCKS), dim3(THREADS), 0, stream>>>(x, Wn, bn, Ws, bs, (float*)d_out);
}

// Round 9
// 153.335 us; speedup vs baseline: 3.4130x; 2.3589x over previous
//
#include <hip/hip_runtime.h>

typedef _Float16 f16;
typedef __attribute__((ext_vector_type(8))) _Float16 f16x8;
typedef __attribute__((ext_vector_type(4))) float    f32x4;

#define NP 13           // Wn0..6 -> p=0..6, Ws0..5 -> p=7..12; result = outputs[7]
#define NLDS 9          // p=0..8 staged in LDS; p=9..12 (Ws2..Ws5) read from d_ws (L2)
#define THREADS 512     // 8 waves/block; LDS ~75.4 KB -> 2 blocks/CU -> 4 waves/SIMD
#define NBLOCKS 512     // 2 blocks/CU across 256 CUs
#define TILES 2         // 4096 waves * 2 tiles * 32 rows = 262144

// Verified (R2-R5) conventions for mfma_f32_16x16x32_f16, D[m][n]=sum_k A[m][k]B[n][k]:
//   A/B frag: lane(q=lane>>4, l15=lane&15) holds [m|n = l15][k = q*8+j], j=0..7
//   C/D:      col(n)=l15, row(m)=q*4+reg
// A = W (m = output feature), B = h (n = batch row). C feeds the next layer's B-frag
// with NO cross-lane movement via the k-slot permutation in the weight layout:
//   chunk ch = kb*4+q holds features kb*32 + jh*16 + q*4 + jl, XOR-swizzled by f&7.
//
// R14 design. Register law (R0/R12/R13): 512-thread builds budget 128 VGPR; R0's exact
// body (runtime l-loop + explicit hp/hp2/hnew copies + bias4 + scalar epilogue) is the
// ONLY shape proven to live under it (124). Macro-unrolled layer chains (R12/R13) let
// the scheduler hoist loads across layers -> spill. So the body below is R0 verbatim.
// The lever is occupancy: 9 mats in LDS (72KB+3.3KB = 75.4KB <= 80KB) -> 2 blocks/CU
// (was 1 at 110KB), doubling waves/SIMD at the SAME proven register budget. The 4
// leftover mats (one per layer 4..7) come from a pre-swizzled f16 image in d_ws built
// by a prep kernel (32KB, L2-resident; ~7 TB/s demand << 34.5 TB/s L2 ceiling).
// 1024-thread shape: closed (R8-R11, always 64 VGPR -> 1.3GB scratch).

// ---- prep: build swizzled f16 weight image + f32 bias image in workspace ----
__global__ __launch_bounds__(256)
void nn_prep(const float* __restrict__ Wn, const float* __restrict__ bn,
             const float* __restrict__ Ws, const float* __restrict__ bs,
             f16* __restrict__ wsw)
{
    const int c = blockIdx.x * 256 + threadIdx.x;      // 26 blocks -> 6656 = NP*512
    if (c < NP * 512) {
        const int p = c >> 9, f = (c >> 3) & 63, ch = c & 7;
        const int kb = ch >> 2, qq = ch & 3;
        const float* src = (p < 7 ? Wn + p * 4096 : Ws + (p - 7) * 4096) + f * 64;
        f32x4 a, b;
        __builtin_memcpy(&a, src + kb * 32 + qq * 4, 16);       // jh=0
        __builtin_memcpy(&b, src + kb * 32 + 16 + qq * 4, 16);  // jh=1
        f16x8 v;
        v[0]=(f16)a.x; v[1]=(f16)a.y; v[2]=(f16)a.z; v[3]=(f16)a.w;
        v[4]=(f16)b.x; v[5]=(f16)b.y; v[6]=(f16)b.z; v[7]=(f16)b.w;
        __builtin_memcpy(wsw + p * 4096 + f * 64 + ((ch ^ (f & 7)) << 3), &v, 16);
    }
    if (c < NP * 64) {                                  // f32 biases after the weights
        const int p = c >> 6, f = c & 63;
        float* bws = (float*)(wsw + NP * 4096);         // offset 106496B, 16B-aligned
        bws[c] = (p < 7) ? bn[p * 64 + f] : bs[(p - 7) * 64 + f];
    }
}

__global__ __launch_bounds__(THREADS)
void nn_fused(const float* __restrict__ x, const f16* __restrict__ wsw,
              float* __restrict__ out)
{
    __shared__ f16   w_lds[NLDS * 4096];   // p=0..8, 72 KB
    __shared__ float b_lds[NP * 64];       // r-strided: [p][(f&3)*16 + (f>>2)]

    const int tid = threadIdx.x;
    const float* bws = (const float*)(wsw + NP * 4096);

    // ---- stage 9 mats: plain 16B copies (pre-swizzled in prep) ----
    for (int c = tid; c < NLDS * 512; c += THREADS) {
        f16x8 v;
        __builtin_memcpy(&v, wsw + c * 8, 16);
        __builtin_memcpy(&w_lds[c * 8], &v, 16);
    }
    // biases r-strided so per-ft reads are 4 separate b32 16-lane broadcasts (R0 pattern)
    for (int i = tid; i < NP * 64; i += THREADS) {
        const int p = i >> 6, f = i & 63;
        b_lds[p * 64 + (f & 3) * 16 + (f >> 2)] = bws[i];
    }
    __syncthreads();   // only barrier in the kernel

    const int lane = tid & 63;
    const int wid  = tid >> 6;
    const int l15  = lane & 15;
    const int q    = lane >> 4;
    const int gw   = blockIdx.x * (THREADS / 64) + wid;   // 0..4095

    auto wfragL = [&](int p, int ft, int kb) -> f16x8 {    // LDS mats p=0..8
        const int f = ft * 16 + l15;
        const int chs = (kb * 4 + q) ^ (f & 7);
        f16x8 v;
        __builtin_memcpy(&v, &w_lds[p * 4096 + f * 64 + (chs << 3)], 16);
        return v;
    };
    auto wfragG = [&](int p, int ft, int kb) -> f16x8 {    // global mats p=9..12 (L2)
        const int f = ft * 16 + l15;
        const int chs = (kb * 4 + q) ^ (f & 7);
        f16x8 v;
        __builtin_memcpy(&v, wsw + p * 4096 + f * 64 + (chs << 3), 16);
        return v;
    };
    auto bias4 = [&](int p, int ft) -> f32x4 {   // bias for features ft*16 + q*4 + r
        f32x4 b;
#pragma unroll
        for (int r = 0; r < 4; ++r) b[r] = b_lds[p * 64 + r * 16 + (ft * 4 + q)];
        return b;
    };

#pragma unroll 1
    for (int t = 0; t < TILES; ++t) {
        const long row0 = ((long)gw + (long)t * (NBLOCKS * THREADS / 64)) * 32;

        f16x8 hp[2][2], hp2[2][2];   // h_{l-1}, h_{l-2} B-frags for 32 batch rows

        // ---- x -> B-frags (into hp2; x is layer-2's skip input) ----
#pragma unroll
        for (int nb = 0; nb < 2; ++nb) {
            const float* xr = x + (row0 + nb * 16 + l15) * 64;
#pragma unroll
            for (int kb = 0; kb < 2; ++kb) {
                f32x4 a, b;
                __builtin_memcpy(&a, xr + kb * 32 + q * 4, 16);
                __builtin_memcpy(&b, xr + kb * 32 + 16 + q * 4, 16);
                f16x8 v;
                v[0]=(f16)a.x; v[1]=(f16)a.y; v[2]=(f16)a.z; v[3]=(f16)a.w;
                v[4]=(f16)b.x; v[5]=(f16)b.y; v[6]=(f16)b.z; v[7]=(f16)b.w;
                hp2[nb][kb] = v;
            }
        }

        // ---- layer 1: hp = relu(x Wn0^T + bn0) ----
#pragma unroll
        for (int ft = 0; ft < 4; ++ft) {
            const f16x8 w0 = wfragL(0, ft, 0), w1 = wfragL(0, ft, 1);
            const f32x4 bv = bias4(0, ft);
#pragma unroll
            for (int nb = 0; nb < 2; ++nb) {
                f32x4 an = bv;
                an = __builtin_amdgcn_mfma_f32_16x16x32_f16(w0, hp2[nb][0], an, 0, 0, 0);
                an = __builtin_amdgcn_mfma_f32_16x16x32_f16(w1, hp2[nb][1], an, 0, 0, 0);
#pragma unroll
                for (int r = 0; r < 4; ++r)
                    hp[nb][ft >> 1][(ft & 1) * 4 + r] = (f16)fmaxf(an[r], 0.f);
            }
        }

        // ---- layers 2..3 (skip mats p=7,8 in LDS) ----
#pragma unroll 1
        for (int l = 2; l <= 3; ++l) {
            const int pn = l - 1, ps = l + 5;
            f16x8 hnew[2][2];
#pragma unroll
            for (int ft = 0; ft < 4; ++ft) {
                const f16x8 wn0 = wfragL(pn, ft, 0), wn1 = wfragL(pn, ft, 1);
                const f16x8 ws0 = wfragL(ps, ft, 0), ws1 = wfragL(ps, ft, 1);
                const f32x4 bnv = bias4(pn, ft),  bsv = bias4(ps, ft);
#pragma unroll
                for (int nb = 0; nb < 2; ++nb) {
                    f32x4 an = bnv, as = bsv;
                    an = __builtin_amdgcn_mfma_f32_16x16x32_f16(wn0, hp[nb][0],  an, 0, 0, 0);
                    an = __builtin_amdgcn_mfma_f32_16x16x32_f16(wn1, hp[nb][1],  an, 0, 0, 0);
                    as = __builtin_amdgcn_mfma_f32_16x16x32_f16(ws0, hp2[nb][0], as, 0, 0, 0);
                    as = __builtin_amdgcn_mfma_f32_16x16x32_f16(ws1, hp2[nb][1], as, 0, 0, 0);
#pragma unroll
                    for (int r = 0; r < 4; ++r)
                        hnew[nb][ft >> 1][(ft & 1) * 4 + r] =
                            (f16)(fmaxf(an[r], 0.f) + fmaxf(as[r], 0.f));
                }
            }
#pragma unroll
            for (int nb = 0; nb < 2; ++nb)
#pragma unroll
            for (int kb = 0; kb < 2; ++kb) {
                hp2[nb][kb] = hp[nb][kb];
                hp[nb][kb]  = hnew[nb][kb];
            }
        }

        // ---- layers 4..6 (skip mats p=9,10,11 from d_ws/L2) ----
#pragma unroll 1
        for (int l = 4; l <= 6; ++l) {
            const int pn = l - 1, ps = l + 5;
            f16x8 hnew[2][2];
#pragma unroll
            for (int ft = 0; ft < 4; ++ft) {
                const f16x8 wn0 = wfragL(pn, ft, 0), wn1 = wfragL(pn, ft, 1);
                const f16x8 ws0 = wfragG(ps, ft, 0), ws1 = wfragG(ps, ft, 1);
                const f32x4 bnv = bias4(pn, ft),  bsv = bias4(ps, ft);
#pragma unroll
                for (int nb = 0; nb < 2; ++nb) {
                    f32x4 an = bnv, as = bsv;
                    an = __builtin_amdgcn_mfma_f32_16x16x32_f16(wn0, hp[nb][0],  an, 0, 0, 0);
                    an = __builtin_amdgcn_mfma_f32_16x16x32_f16(wn1, hp[nb][1],  an, 0, 0, 0);
                    as = __builtin_amdgcn_mfma_f32_16x16x32_f16(ws0, hp2[nb][0], as, 0, 0, 0);
                    as = __builtin_amdgcn_mfma_f32_16x16x32_f16(ws1, hp2[nb][1], as, 0, 0, 0);
#pragma unroll
                    for (int r = 0; r < 4; ++r)
                        hnew[nb][ft >> 1][(ft & 1) * 4 + r] =
                            (f16)(fmaxf(an[r], 0.f) + fmaxf(as[r], 0.f));
                }
            }
#pragma unroll
            for (int nb = 0; nb < 2; ++nb)
#pragma unroll
            for (int kb = 0; kb < 2; ++kb) {
                hp2[nb][kb] = hp[nb][kb];
                hp[nb][kb]  = hnew[nb][kb];
            }
        }

        // ---- layer 7: out = relu(h6 Wn6^T + bn6) + relu(h5 Ws5^T + bs5), fp32 store ----
#pragma unroll
        for (int ft = 0; ft < 4; ++ft) {
            const f16x8 wn0 = wfragL(6, ft, 0),  wn1 = wfragL(6, ft, 1);
            const f16x8 ws0 = wfragG(12, ft, 0), ws1 = wfragG(12, ft, 1);
            const f32x4 bnv = bias4(6, ft),      bsv = bias4(12, ft);
#pragma unroll
            for (int nb = 0; nb < 2; ++nb) {
                f32x4 an = bnv, as = bsv;
                an = __builtin_amdgcn_mfma_f32_16x16x32_f16(wn0, hp[nb][0],  an, 0, 0, 0);
                an = __builtin_amdgcn_mfma_f32_16x16x32_f16(wn1, hp[nb][1],  an, 0, 0, 0);
                as = __builtin_amdgcn_mfma_f32_16x16x32_f16(ws0, hp2[nb][0], as, 0, 0, 0);
                as = __builtin_amdgcn_mfma_f32_16x16x32_f16(ws1, hp2[nb][1], as, 0, 0, 0);
                f32x4 v;
#pragma unroll
                for (int r = 0; r < 4; ++r) v[r] = fmaxf(an[r], 0.f) + fmaxf(as[r], 0.f);
                float* orow = out + (row0 + nb * 16 + l15) * 64;
                __builtin_memcpy(orow + ft * 16 + q * 4, &v, 16);
            }
        }
    }
}

extern "C" void kernel_launch(void* const* d_in, const int* in_sizes, int n_in,
                              void* d_out, int out_size, void* d_ws, size_t ws_size,
                              hipStream_t stream) {
    (void)in_sizes; (void)n_in; (void)ws_size; (void)out_size;
    const float* x  = (const float*)d_in[0];
    const float* Wn = (const float*)d_in[1];
    const float* bn = (const float*)d_in[2];
    const float* Ws = (const float*)d_in[3];
    const float* bs = (const float*)d_in[4];
    f16* wsw = (f16*)d_ws;   // needs NP*4096*2 + NP*64*4 = 109824 B
    nn_prep<<<dim3(26), dim3(256), 0, stream>>>(Wn, bn, Ws, bs, wsw);
    nn_fused<<<dim3(NBLOCKS), dim3(THREADS), 0, stream>>>(x, wsw, (float*)d_out);
}